// Round 20
// baseline (204.185 us; speedup 1.0000x reference)
//
#include <hip/hip_runtime.h>

// Guided filter r=8 (K=17), eps=0.1, (8,3,1024,1024); f32 in / f32 out.
// V12: 64x32 tile, 384 threads, quad arena [48 rows][97 f4] (74.5 KB,
// 2 blocks/CU = 12 waves/CU), launch_bounds(384,1) (R18's VGPR=56 fix),
// interior fast-path in phase A (94% of blocks skip per-row reflect),
// rcp-folded ab math, C in 8-row strips.
//
//   A : vertical 17-tap sliding sums {I,p,Ip,II}, 384 units (96 cols x
//       4 chunks of 12 rows), 28-row reg window, 12 b128 writes
//   B1: horizontal 17-sums, 384 units (48 rows x 8 blocks of 10 ab-cols),
//       26 b128 reads (slide window 9+9 quads in regs) -> a,b; write pairs
//   B2: horizontal 17-sums of (a,b), 384 units (48 x 8 blocks of 8),
//       12 b128 reads -> (hsA,hsB) pairs at f4 cols 40..71
//   C : vertical 17-sums, 256 units (64 cols x 4 strips of 8 rows),
//       24 b64 reads + out = INV*fma(sa,I,sb)

#define TW 64
#define TH 32
#define AR 48
#define F4STR 97                   // float4 per row
#define INV_AREA (1.0f / 289.0f)

__device__ __forceinline__ int refl1024(int v) {
    v = (v < 0) ? -v : v;
    v = (v > 1023) ? 2046 - v : v;
    if (v < 0) v = 0;
    if (v > 1023) v = 1023;
    return v;
}

__global__ __launch_bounds__(384, 1) void gf_fused(
    const float* __restrict__ P, const float* __restrict__ I,
    float* __restrict__ O, int H, int W)
{
    __shared__ __align__(16) float4 S4[AR * F4STR];   // 74496 B
    float2* __restrict__ Sf2 = (float2*)S4;

    const int tid = threadIdx.x;
    const int tx0 = blockIdx.x * TW;
    const int ty0 = blockIdx.y * TH;
    const size_t plane = (size_t)blockIdx.z * H * W;
    const float* __restrict__ Ic = I + plane;
    const float* __restrict__ Pc = P + plane;

    // ---------------- Phase A: vertical sliding sums -> quads ---------------
    {
        const int chunk = tid / 96;                    // 0..3
        const int col   = tid - chunk * 96;            // vs col 0..95
        const int r0    = chunk * 12;
        const int gx    = refl1024(tx0 + col - 16);

        float vI[28], vP[28];
        if (ty0 >= 16 && ty0 <= 976) {
            // interior: rows ty0+r0-16 .. ty0+r0+11+16 all in [0,1023]
            const float* __restrict__ rI = Ic + (size_t)(ty0 + r0 - 16) * W + gx;
            const float* __restrict__ rP = Pc + (size_t)(ty0 + r0 - 16) * W + gx;
            #pragma unroll
            for (int j = 0; j < 28; ++j) {
                vI[j] = rI[(size_t)j * W];
                vP[j] = rP[(size_t)j * W];
            }
        } else {
            #pragma unroll
            for (int j = 0; j < 28; ++j) {
                const int gy = refl1024(ty0 + r0 - 16 + j);
                const size_t g = (size_t)gy * W + gx;
                vI[j] = Ic[g];
                vP[j] = Pc[g];
            }
        }
        float s0 = 0.f, s1 = 0.f, s2 = 0.f, s3 = 0.f;
        #pragma unroll
        for (int j = 0; j < 17; ++j) {
            s0 += vI[j]; s1 += vP[j];
            s2 += vI[j] * vP[j];
            s3 += vI[j] * vI[j];
        }
        S4[r0 * F4STR + col] = make_float4(s0, s1, s2, s3);
        #pragma unroll
        for (int o = 1; o < 12; ++o) {
            const float ni = vI[o + 16], oi = vI[o - 1];
            const float np_ = vP[o + 16], op_ = vP[o - 1];
            s0 += ni - oi;
            s1 += np_ - op_;
            s2 += ni * np_ - oi * op_;
            s3 += ni * ni - oi * oi;
            S4[(r0 + o) * F4STR + col] = make_float4(s0, s1, s2, s3);
        }
    }
    __syncthreads();

    // ---------------- Phase B1: horizontal sums -> a,b ----------------------
    // 384 units: brow=(tid&7)+8*(tid>>6) in 0..47, blk=(tid>>3)&7.
    // ab cols blk*10..+9 (img col tx0+c-8); window vs quads [c, c+25].
    const int brow = (tid & 7) + ((tid >> 6) << 3);
    const int blk  = (tid >> 3) & 7;
    float oa[10], ob[10];
    {
        float k0l[9], k1l[9], k2l[9], k3l[9];
        float k0h[9], k1h[9], k2h[9], k3h[9];
        float s0 = 0.f, s1 = 0.f, s2 = 0.f, s3 = 0.f;
        #pragma unroll
        for (int j = 0; j < 26; ++j) {
            const float4 w = S4[brow * F4STR + blk * 10 + j];
            if (j < 17) { s0 += w.x; s1 += w.y; s2 += w.z; s3 += w.w; }
            if (j < 9)  { k0l[j] = w.x; k1l[j] = w.y; k2l[j] = w.z; k3l[j] = w.w; }
            if (j >= 17) {
                const int m = j - 17;
                k0h[m] = w.x; k1h[m] = w.y; k2h[m] = w.z; k3h[m] = w.w;
            }
        }
        #pragma unroll
        for (int o = 0; o < 10; ++o) {
            if (o) {
                s0 += k0h[o - 1] - k0l[o - 1];
                s1 += k1h[o - 1] - k1l[o - 1];
                s2 += k2h[o - 1] - k2l[o - 1];
                s3 += k3h[o - 1] - k3l[o - 1];
            }
            const float num = fmaf(289.0f, s2, -s0 * s1);
            const float den = fmaf(289.0f, s3, -s0 * s0) + 8352.1f; // 289^2*0.1
            const float av  = num * __builtin_amdgcn_rcpf(den);
            oa[o] = av;
            ob[o] = fmaf(-av, s0, s1) * INV_AREA;
        }
    }
    __syncthreads();
    // (a,b) pairs over f4 cols 0..39 (5 per block)
    #pragma unroll
    for (int t = 0; t < 5; ++t)
        S4[brow * F4STR + blk * 5 + t] =
            make_float4(oa[2 * t], ob[2 * t], oa[2 * t + 1], ob[2 * t + 1]);
    __syncthreads();

    // ---------------- Phase B2: horizontal sums of (a,b) -> hs pairs --------
    // hs cols blk*8..+7 (img tx0+x); window ab cols [x, x+16] in pairs blk*4+t.
    {
        float qa[24], qb[24];
        #pragma unroll
        for (int t = 0; t < 12; ++t) {
            const float4 w = S4[brow * F4STR + blk * 4 + t];
            qa[2 * t] = w.x;     qb[2 * t] = w.y;
            qa[2 * t + 1] = w.z; qb[2 * t + 1] = w.w;
        }
        float hsA[8], hsB[8];
        float sa = 0.f, sb = 0.f;
        #pragma unroll
        for (int j = 0; j < 17; ++j) { sa += qa[j]; sb += qb[j]; }
        hsA[0] = sa; hsB[0] = sb;
        #pragma unroll
        for (int o = 1; o < 8; ++o) {
            sa += qa[o + 16] - qa[o - 1];
            sb += qb[o + 16] - qb[o - 1];
            hsA[o] = sa; hsB[o] = sb;
        }
        // (hsA,hsB) pairs at f4 cols 40..71 (disjoint from ab 0..39 -> no barrier)
        #pragma unroll
        for (int t = 0; t < 4; ++t)
            S4[brow * F4STR + 40 + blk * 4 + t] =
                make_float4(hsA[2 * t], hsB[2 * t], hsA[2 * t + 1], hsB[2 * t + 1]);
    }
    __syncthreads();

    // ---------------- Phase C: vertical sums + finale -----------------------
    // 256 units: ox = tid&63, oy0 = (tid>>6)*8 -> 8 px each.
    if (tid < 256) {
        const int ox  = tid & 63;
        const int oy0 = (tid >> 6) << 3;   // 0,8,16,24
        float ca[24], cb[24];
        #pragma unroll
        for (int j = 0; j < 24; ++j) {
            const float2 w = Sf2[(oy0 + j) * (F4STR * 2) + 80 + ox];
            ca[j] = w.x; cb[j] = w.y;
        }
        float sa = 0.f, sb = 0.f;
        #pragma unroll
        for (int j = 0; j < 17; ++j) { sa += ca[j]; sb += cb[j]; }
        #pragma unroll
        for (int o = 0; o < 8; ++o) {
            if (o) {
                sa += ca[o + 16] - ca[o - 1];
                sb += cb[o + 16] - cb[o - 1];
            }
            const size_t gp = (size_t)(ty0 + oy0 + o) * W + (tx0 + ox);
            O[plane + gp] = INV_AREA * fmaf(sa, Ic[gp], sb);
        }
    }
}

extern "C" void kernel_launch(void* const* d_in, const int* in_sizes, int n_in,
                              void* d_out, int out_size, void* d_ws, size_t ws_size,
                              hipStream_t stream) {
    const int H = 1024, W = 1024;
    if (n_in < 2) return;
    const long long npx = (long long)H * W;
    const long long n0 = in_sizes[0];
    if (n0 <= 0 || (n0 % npx) != 0) return;
    if ((long long)out_size != n0) return;
    if (in_sizes[1] != in_sizes[0]) return;
    const int NP = (int)(n0 / npx);

    const float* p = (const float*)d_in[0];   // input_img
    const float* I = (const float*)d_in[1];   // guide_img
    float* out = (float*)d_out;

    dim3 grid(W / TW, H / TH, NP);
    gf_fused<<<grid, 384, 0, stream>>>(p, I, out, H, W);
}

// Round 21
// 145.711 us; speedup vs baseline: 1.4013x; 1.4013x over previous
//
#include <hip/hip_runtime.h>

// Guided filter r=8 (K=17), eps=0.1, (8,3,1024,1024); f32 in / f32 out.
// V13 = R16 (best, 152.6us) + two isolated micro-opts:
//   1. Phase-A interior fast-path: blocks with ty0 in [16,976] (94%) skip
//      per-row reflect; single base pointer + constant row-stride loads.
//   2. Phase C in 8-row strips (128 threads x 8 rows): LDS reads 5 -> 3 /px.
// Structure frozen: 32x32 tile, 256 thr, 4-plane arena [48][68] f32 (52.2 KB,
// 3 blocks/CU), rcp-folded ab math, R12 B-map, 4+1 barriers.

#define TW 32
#define TH 32
#define STRD 68                    // words; 272 B rows
#define VROWS 48
#define PL (VROWS * STRD)          // 3264 words/plane
#define PL4 (PL / 4)               // 816 float4/plane
#define INV_AREA (1.0f / 289.0f)

__device__ __forceinline__ int refl1024(int v) {
    v = (v < 0) ? -v : v;
    v = (v > 1023) ? 2046 - v : v;
    if (v < 0) v = 0;
    if (v > 1023) v = 1023;
    return v;
}

__global__ __launch_bounds__(256) void gf_fused(
    const float* __restrict__ P, const float* __restrict__ I,
    float* __restrict__ O, int H, int W)
{
    __shared__ __align__(16) float4 S4[4 * PL4];   // 52224 B
    float* __restrict__ Sf = (float*)S4;

    const int tid = threadIdx.x;
    const int tx0 = blockIdx.x * TW;
    const int ty0 = blockIdx.y * TH;
    const size_t plane = (size_t)blockIdx.z * H * W;
    const float* __restrict__ Ic = I + plane;
    const float* __restrict__ Pc = P + plane;

    // ---------------- Phase A: vertical sliding sums ------------------------
    {
        const int vc = tid & 63;                                   // vs col
        const int ck = __builtin_amdgcn_readfirstlane(tid >> 6);   // wave-uniform
        const int r0 = ck * 12;
        const int gx = refl1024(tx0 + vc - 16);

        float vI[28], vP[28];
        if (ty0 >= 16 && ty0 <= 976) {
            // interior: rows ty0+r0-16 .. ty0+r0+27-16 all in [0,1023]
            const float* __restrict__ rI = Ic + (size_t)(ty0 + r0 - 16) * W + gx;
            const float* __restrict__ rP = Pc + (size_t)(ty0 + r0 - 16) * W + gx;
            #pragma unroll
            for (int j = 0; j < 28; ++j) {
                vI[j] = rI[(size_t)j * W];
                vP[j] = rP[(size_t)j * W];
            }
        } else {
            #pragma unroll
            for (int j = 0; j < 28; ++j) {
                const int gy = refl1024(ty0 + r0 - 16 + j);        // scalar
                const float* __restrict__ rI = Ic + (size_t)gy * W;
                const float* __restrict__ rP = Pc + (size_t)gy * W;
                vI[j] = rI[gx];
                vP[j] = rP[gx];
            }
        }
        float s0 = 0.f, s1 = 0.f, s2 = 0.f, s3 = 0.f;
        #pragma unroll
        for (int j = 0; j < 17; ++j) {
            s0 += vI[j]; s1 += vP[j];
            s2 += vI[j] * vP[j];
            s3 += vI[j] * vI[j];
        }
        Sf[0 * PL + r0 * STRD + vc] = s0;
        Sf[1 * PL + r0 * STRD + vc] = s1;
        Sf[2 * PL + r0 * STRD + vc] = s2;
        Sf[3 * PL + r0 * STRD + vc] = s3;
        #pragma unroll
        for (int o = 1; o < 12; ++o) {
            const float ni = vI[o + 16], oi = vI[o - 1];
            const float np_ = vP[o + 16], op_ = vP[o - 1];
            s0 += ni - oi;
            s1 += np_ - op_;
            s2 += ni * np_ - oi * op_;
            s3 += ni * ni - oi * oi;
            Sf[0 * PL + (r0 + o) * STRD + vc] = s0;
            Sf[1 * PL + (r0 + o) * STRD + vc] = s1;
            Sf[2 * PL + (r0 + o) * STRD + vc] = s2;
            Sf[3 * PL + (r0 + o) * STRD + vc] = s3;
        }
    }
    __syncthreads();

    // ---------------- Phase B1: horizontal sums -> a,b ----------------------
    const int vr = (tid & 15) + ((tid >> 6) << 4);   // 0..47 (tid<192)
    const int u4 = (tid >> 4) & 3;                   // col-block (12 ab cols)
    float oa[12], ob[12];
    if (tid < 192) {
        float sm[4][12];
        #pragma unroll
        for (int q = 0; q < 4; ++q) {
            float vv[28];
            #pragma unroll
            for (int t = 0; t < 7; ++t) {
                const float4 w = S4[q * PL4 + vr * 17 + u4 * 3 + t];
                vv[4 * t + 0] = w.x; vv[4 * t + 1] = w.y;
                vv[4 * t + 2] = w.z; vv[4 * t + 3] = w.w;
            }
            float sacc = 0.f;
            #pragma unroll
            for (int j = 0; j < 17; ++j) sacc += vv[j];
            sm[q][0] = sacc;
            #pragma unroll
            for (int o = 1; o < 12; ++o) {
                sacc += vv[o + 16] - vv[o - 1];
                sm[q][o] = sacc;
            }
        }
        #pragma unroll
        for (int o = 0; o < 12; ++o) {
            const float s0 = sm[0][o], s1 = sm[1][o];
            const float s2 = sm[2][o], s3 = sm[3][o];
            const float num = fmaf(289.0f, s2, -s0 * s1);
            const float den = fmaf(289.0f, s3, -s0 * s0) + 8352.1f; // 289^2*0.1
            const float av  = num * __builtin_amdgcn_rcpf(den);
            oa[o] = av;
            ob[o] = fmaf(-av, s0, s1) * INV_AREA;
        }
    }
    __syncthreads();
    if (tid < 192) {
        #pragma unroll
        for (int t = 0; t < 3; ++t) {
            S4[0 * PL4 + vr * 17 + u4 * 3 + t] =
                make_float4(oa[4 * t], oa[4 * t + 1], oa[4 * t + 2], oa[4 * t + 3]);
            S4[1 * PL4 + vr * 17 + u4 * 3 + t] =
                make_float4(ob[4 * t], ob[4 * t + 1], ob[4 * t + 2], ob[4 * t + 3]);
        }
    }
    __syncthreads();

    // ---------------- Phase B2: horizontal sums of a,b -> planes 2,3 --------
    if (tid < 192) {
        float va[24], vb[24];
        #pragma unroll
        for (int t = 0; t < 6; ++t) {
            const float4 wa = S4[0 * PL4 + vr * 17 + u4 * 2 + t];
            const float4 wb = S4[1 * PL4 + vr * 17 + u4 * 2 + t];
            va[4 * t + 0] = wa.x; va[4 * t + 1] = wa.y;
            va[4 * t + 2] = wa.z; va[4 * t + 3] = wa.w;
            vb[4 * t + 0] = wb.x; vb[4 * t + 1] = wb.y;
            vb[4 * t + 2] = wb.z; vb[4 * t + 3] = wb.w;
        }
        float hsA[8], hsB[8];
        float sa = 0.f, sb = 0.f;
        #pragma unroll
        for (int j = 0; j < 17; ++j) { sa += va[j]; sb += vb[j]; }
        hsA[0] = sa; hsB[0] = sb;
        #pragma unroll
        for (int o = 1; o < 8; ++o) {
            sa += va[o + 16] - va[o - 1];
            sb += vb[o + 16] - vb[o - 1];
            hsA[o] = sa; hsB[o] = sb;
        }
        #pragma unroll
        for (int t = 0; t < 2; ++t) {
            S4[2 * PL4 + vr * 17 + u4 * 2 + t] =
                make_float4(hsA[4 * t], hsA[4 * t + 1], hsA[4 * t + 2], hsA[4 * t + 3]);
            S4[3 * PL4 + vr * 17 + u4 * 2 + t] =
                make_float4(hsB[4 * t], hsB[4 * t + 1], hsB[4 * t + 2], hsB[4 * t + 3]);
        }
    }
    __syncthreads();

    // ---------------- Phase C: vertical sums + finale (8-row strips) --------
    if (tid < 128) {
        const int ox  = tid & 31;
        const int oy0 = (tid >> 5) << 3;   // 0,8,16,24
        float ca[24], cb[24];
        #pragma unroll
        for (int j = 0; j < 24; ++j) {
            ca[j] = Sf[2 * PL + (oy0 + j) * STRD + ox];
            cb[j] = Sf[3 * PL + (oy0 + j) * STRD + ox];
        }
        float sa = 0.f, sb = 0.f;
        #pragma unroll
        for (int j = 0; j < 17; ++j) { sa += ca[j]; sb += cb[j]; }
        #pragma unroll
        for (int o = 0; o < 8; ++o) {
            if (o) {
                sa += ca[o + 16] - ca[o - 1];
                sb += cb[o + 16] - cb[o - 1];
            }
            const size_t gp = (size_t)(ty0 + oy0 + o) * W + (tx0 + ox);
            O[plane + gp] = INV_AREA * fmaf(sa, Ic[gp], sb);
        }
    }
}

extern "C" void kernel_launch(void* const* d_in, const int* in_sizes, int n_in,
                              void* d_out, int out_size, void* d_ws, size_t ws_size,
                              hipStream_t stream) {
    const int H = 1024, W = 1024;
    if (n_in < 2) return;
    const long long npx = (long long)H * W;
    const long long n0 = in_sizes[0];
    if (n0 <= 0 || (n0 % npx) != 0) return;
    if ((long long)out_size != n0) return;
    if (in_sizes[1] != in_sizes[0]) return;
    const int NP = (int)(n0 / npx);

    const float* p = (const float*)d_in[0];   // input_img
    const float* I = (const float*)d_in[1];   // guide_img
    float* out = (float*)d_out;

    dim3 grid(W / TW, H / TH, NP);
    gf_fused<<<grid, 256, 0, stream>>>(p, I, out, H, W);
}